// Round 14
// baseline (587.002 us; speedup 1.0000x reference)
//
#include <hip/hip_runtime.h>

typedef __bf16 bf16_t;
typedef __bf16 bf16x8 __attribute__((ext_vector_type(8)));
typedef __bf16 bf16x4 __attribute__((ext_vector_type(4)));
typedef __bf16 bf16x2 __attribute__((ext_vector_type(2)));
typedef float  f32x4  __attribute__((ext_vector_type(4)));
typedef float  f32x16 __attribute__((ext_vector_type(16)));
typedef unsigned int u32x4 __attribute__((ext_vector_type(4)));

#define MFMA16(a, b, c) __builtin_amdgcn_mfma_f32_16x16x32_bf16((a), (b), (c), 0, 0, 0)
#define MFMA32(a, b, c) __builtin_amdgcn_mfma_f32_32x32x16_bf16((a), (b), (c), 0, 0, 0)

__device__ __forceinline__ void async_load16(const void* g, void* l) {
    __builtin_amdgcn_global_load_lds(
        (const __attribute__((address_space(1))) void*)g,
        (__attribute__((address_space(3))) void*)l, 16, 0, 0);
}

__device__ __forceinline__ unsigned pack2(float a, float b) {
    bf16x2 t;
    t[0] = (bf16_t)a;
    t[1] = (bf16_t)b;
    return __builtin_bit_cast(unsigned, t);
}

// ---------------------------------------------------------------- fp32 -> bf16 (3 tensors, one launch)
__global__ void cvt3_f32_to_bf16(const float* __restrict__ s0, bf16_t* __restrict__ d0, int n0,
                                 const float* __restrict__ s1, bf16_t* __restrict__ d1, int n1,
                                 const float* __restrict__ s2, bf16_t* __restrict__ d2, int n2) {
    const float* s; bf16_t* d; int n, bl, nb;
    const int bid = blockIdx.x;
    if (bid < 512)       { s = s0; d = d0; n = n0; bl = bid;        nb = 512; }
    else if (bid < 1280) { s = s1; d = d1; n = n1; bl = bid - 512;  nb = 768; }
    else                 { s = s2; d = d2; n = n2; bl = bid - 1280; nb = 512; }
    const int stride4 = nb * blockDim.x * 4;
    for (int j = (bl * blockDim.x + threadIdx.x) * 4; j < n; j += stride4) {
        float4 v = *(const float4*)(s + j);
        bf16x4 o = { (bf16_t)v.x, (bf16_t)v.y, (bf16_t)v.z, (bf16_t)v.w };
        *(bf16x4*)(d + j) = o;
    }
}

__device__ __forceinline__ void storeC(float* C, size_t idx, float v)  { C[idx] = v; }
__device__ __forceinline__ void storeC(bf16_t* C, size_t idx, float v) { C[idx] = (bf16_t)v; }

// ---------------------------------------------------------------- QKV GEMM: exact 256-block grid
__global__ __launch_bounds__(512, 2) void gemm_qkv(const bf16_t* __restrict__ A,
                                                   const bf16_t* __restrict__ B,
                                                   bf16_t* __restrict__ C,
                                                   int M, int N, int K) {
    __shared__ __align__(16) bf16_t ldsA[2][256][64];   // 64 KiB
    __shared__ __align__(16) bf16_t ldsB[2][192][64];   // 48 KiB
    const int tid  = threadIdx.x;
    const int lane = tid & 63;
    const int wid  = tid >> 6;
    const int lrow = lane & 15, lhi = lane >> 4;
    const int wrow = (wid >> 1) * 64;   // 4 M-waves
    const int wcol = (wid & 1) * 96;    // 2 N-waves
    const int NT = K >> 6;              // 64

    const int nwg = gridDim.x;          // 256
    const int w = ((int)blockIdx.x & 7) * (nwg >> 3) + ((int)blockIdx.x >> 3);
    const int nbx = N / 384;            // 16
    const size_t m0 = (size_t)(w / nbx) * 256;
    const size_t n0b = (size_t)(w % nbx) * 384;

    const int cm = (((lrow & 1) << 5) | ((lrow & 2) << 3) | ((lrow & 4) << 1));  // elem units

    const bf16_t* Am = A + m0 * K;

    auto stageA = [&](int bufi, int k0) {
#pragma unroll
        for (int c = 0; c < 4; ++c) {
            int q = tid + 512 * c;
            int row = q >> 3, slot = q & 7;
            int gc = (slot * 8) ^ (((row & 1) << 5) | ((row & 2) << 3) | ((row & 4) << 1));
            async_load16(Am + (size_t)row * K + k0 + gc, &ldsA[bufi][0][0] + q * 8);
        }
    };
    auto stageB = [&](const bf16_t* Bn, int bufi, int k0) {
#pragma unroll
        for (int c = 0; c < 3; ++c) {
            int q = tid + 512 * c;
            int row = q >> 3, slot = q & 7;
            int gc = (slot * 8) ^ (((row & 1) << 5) | ((row & 2) << 3) | ((row & 4) << 1));
            async_load16(Bn + (size_t)row * K + k0 + gc, &ldsB[bufi][0][0] + q * 8);
        }
    };

    for (int half = 0; half < 2; ++half) {
        const bf16_t* Bn = B + (n0b + half * 192) * K;

        f32x4 acc[4][6];
        const f32x4 vz = {0.f, 0.f, 0.f, 0.f};
#pragma unroll
        for (int i = 0; i < 4; ++i)
#pragma unroll
            for (int j = 0; j < 6; ++j) acc[i][j] = vz;

        stageA(0, 0);
        stageB(Bn, 0, 0);
        stageA(1, 64);
        stageB(Bn, 1, 64);
        asm volatile("s_waitcnt vmcnt(7)" ::: "memory");
        __builtin_amdgcn_s_barrier();

        for (int u = 0; u < NT; ++u) {
            const int cur = u & 1;
            __builtin_amdgcn_s_setprio(1);
#pragma unroll
            for (int kk = 0; kk < 2; ++kk) {
                const int cb = kk * 32 + lhi * 8;
                bf16x8 af[4], bfv[6];
#pragma unroll
                for (int i = 0; i < 4; ++i)
                    af[i] = *(const bf16x8*)(&ldsA[cur][wrow + i * 16 + lrow][0] + (cb ^ cm));
#pragma unroll
                for (int j = 0; j < 6; ++j)
                    bfv[j] = *(const bf16x8*)(&ldsB[cur][wcol + j * 16 + lrow][0] + (cb ^ cm));
#pragma unroll
                for (int i = 0; i < 4; ++i)
#pragma unroll
                    for (int j = 0; j < 6; ++j)
                        acc[i][j] = MFMA16(af[i], bfv[j], acc[i][j]);
            }
            __builtin_amdgcn_s_setprio(0);
            __builtin_amdgcn_s_barrier();
            if (u + 2 < NT) {
                stageA(cur, (u + 2) * 64);
                stageB(Bn, cur, (u + 2) * 64);
            }
            if (u == NT - 2)     asm volatile("s_waitcnt vmcnt(0)" ::: "memory");
            else if (u < NT - 2) asm volatile("s_waitcnt vmcnt(7)" ::: "memory");
            __builtin_amdgcn_s_barrier();
        }

#pragma unroll
        for (int i = 0; i < 4; ++i)
#pragma unroll
            for (int j = 0; j < 6; ++j)
#pragma unroll
                for (int r = 0; r < 4; ++r) {
                    size_t row = m0 + wrow + i * 16 + lhi * 4 + r;
                    size_t col = n0b + half * 192 + wcol + j * 16 + lrow;
                    C[row * (size_t)N + col] = (bf16_t)acc[i][j][r];
                }
    }
}

// ---------------------------------------------------------------- 256x256 GEMM (B^T), BK=64 (dense)
template <typename OT>
__global__ __launch_bounds__(512, 2) void gemm256(const bf16_t* __restrict__ A,
                                                  const bf16_t* __restrict__ B,
                                                  OT* __restrict__ C,
                                                  int M, int N, int K) {
    __shared__ __align__(16) bf16_t lds[2][2][2][128][64];
    const int tid  = threadIdx.x;
    const int lane = tid & 63;
    const int wid  = tid >> 6;
    const int lrow = lane & 15, lhi = lane >> 4;
    const int wrow = (wid >> 2) * 64;
    const int wcol = (wid & 3) * 32;
    const int NT = K >> 6;
    const int nbx = N >> 8;

    const int nwg = gridDim.x;
    const int w = ((int)blockIdx.x & 7) * (nwg >> 3) + ((int)blockIdx.x >> 3);
    const size_t m0 = (size_t)(w / nbx) * 256;
    const size_t n0 = (size_t)(w % nbx) * 256;

    const int cmask = ((lrow & 1) << 5) | ((lrow & 2) << 3) | ((lrow & 4) << 1);
    const int cK0 = (lhi * 8) ^ cmask;
    const int cK1 = (32 + lhi * 8) ^ cmask;
    const int r8 = lane >> 3;
    const int gcol = ((lane & 7) * 8) ^ (((r8 & 1) << 5) | ((r8 & 2) << 3) | ((r8 & 4) << 1));

    auto stage = [&](const bf16_t* srcBase, bf16_t* region) {
#pragma unroll
        for (int c = 0; c < 2; ++c)
            async_load16(srcBase + (size_t)(c * 64 + wid * 8 + r8) * K + gcol,
                         region + c * 4096 + wid * 512);
    };

    int buf = 0;
    bf16x8 af[2][4];
    bf16x8 b0f[2][2], b1f[2][2];

    auto loadA = [&](int mh) {
#pragma unroll
        for (int i = 0; i < 4; ++i) {
            const bf16_t* rp = &lds[buf][0][mh][wrow + i * 16 + lrow][0];
            af[0][i] = *(const bf16x8*)(rp + cK0);
            af[1][i] = *(const bf16x8*)(rp + cK1);
        }
    };
    auto loadB = [&](int nh, bf16x8 (&bf)[2][2]) {
#pragma unroll
        for (int j = 0; j < 2; ++j) {
            const bf16_t* rp = &lds[buf][1][nh][wcol + j * 16 + lrow][0];
            bf[0][j] = *(const bf16x8*)(rp + cK0);
            bf[1][j] = *(const bf16x8*)(rp + cK1);
        }
    };
    auto mmacc = [&](f32x4 (&acc)[4][2], bf16x8 (&bf)[2][2]) {
#pragma unroll
        for (int kk = 0; kk < 2; ++kk)
#pragma unroll
            for (int i = 0; i < 4; ++i)
#pragma unroll
                for (int j = 0; j < 2; ++j)
                    acc[i][j] = MFMA16(af[kk][i], bf[kk][j], acc[i][j]);
    };

    f32x4 a00[4][2], a01[4][2], a10[4][2], a11[4][2];
    const f32x4 vz = {0.f, 0.f, 0.f, 0.f};
#pragma unroll
    for (int i = 0; i < 4; ++i)
#pragma unroll
        for (int j = 0; j < 2; ++j) { a00[i][j] = vz; a01[i][j] = vz; a10[i][j] = vz; a11[i][j] = vz; }

    const bf16_t* Am = A + m0 * K;
    const bf16_t* Bn = B + n0 * K;

    stage(Am,                     &lds[0][0][0][0][0]);
    stage(Bn,                     &lds[0][1][0][0][0]);
    stage(Bn + (size_t)128 * K,   &lds[0][1][1][0][0]);
    stage(Am + (size_t)128 * K,   &lds[0][0][1][0][0]);
    stage(Am + 64,                &lds[1][0][0][0][0]);
    stage(Bn + 64,                &lds[1][1][0][0][0]);
    asm volatile("s_waitcnt vmcnt(4)" ::: "memory");
    __builtin_amdgcn_s_barrier();

    for (int u = 0; u < NT; ++u, buf ^= 1) {
        loadA(0);
        loadB(0, b0f);
        loadB(1, b1f);
        __builtin_amdgcn_s_barrier();
        asm volatile("s_waitcnt lgkmcnt(0)" ::: "memory");
        if (u + 1 < NT) {
            stage(Bn + (size_t)(u + 1) * 64 + (size_t)128 * K, &lds[buf ^ 1][1][1][0][0]);
            stage(Am + (size_t)(u + 1) * 64 + (size_t)128 * K, &lds[buf ^ 1][0][1][0][0]);
        }
        __builtin_amdgcn_s_setprio(1);
        mmacc(a00, b0f);
        mmacc(a01, b1f);
        __builtin_amdgcn_s_setprio(0);
        __builtin_amdgcn_s_barrier();
        loadA(1);
        __builtin_amdgcn_s_barrier();
        asm volatile("s_waitcnt lgkmcnt(0)" ::: "memory");
        if (u + 2 < NT) {
            stage(Am + (size_t)(u + 2) * 64, &lds[buf][0][0][0][0]);
            stage(Bn + (size_t)(u + 2) * 64, &lds[buf][1][0][0][0]);
        }
        __builtin_amdgcn_s_setprio(1);
        mmacc(a10, b0f);
        mmacc(a11, b1f);
        __builtin_amdgcn_s_setprio(0);
        if (u == NT - 2)     asm volatile("s_waitcnt vmcnt(0)" ::: "memory");
        else if (u < NT - 2) asm volatile("s_waitcnt vmcnt(4)" ::: "memory");
        __builtin_amdgcn_s_barrier();
    }

    auto storeQ = [&](f32x4 (&acc)[4][2], int mq, int nq) {
#pragma unroll
        for (int i = 0; i < 4; ++i)
#pragma unroll
            for (int j = 0; j < 2; ++j)
#pragma unroll
                for (int r = 0; r < 4; ++r) {
                    size_t row = m0 + mq * 128 + wrow + i * 16 + lhi * 4 + r;
                    size_t col = n0 + nq * 128 + wcol + j * 16 + lrow;
                    storeC(C, row * (size_t)N + col, acc[i][j][r]);
                }
    };
    storeQ(a00, 0, 0); storeQ(a01, 0, 1); storeQ(a10, 1, 0); storeQ(a11, 1, 1);
}

// ---------------------------------------------------------------- RoPE + scatter q/k
__global__ void rope_scatter(const bf16_t* __restrict__ fused, const int* __restrict__ pos_ids,
                             bf16_t* __restrict__ Q, bf16_t* __restrict__ Kb) {
    const int token = blockIdx.x;
    const int b = token >> 11, s = token & 2047;
    const int d = threadIdx.x;
    const float pos = (float)pos_ids[token];
    const float inv = __expf(-(float)d * (9.210340371976184f / 64.0f));
    float sn, c;
    sincosf(pos * inv, &sn, &c);
    const bf16_t* frow = fused + (size_t)token * 6144;
    for (int it = 0; it < 5; ++it) {
        int ss = it * 8 + threadIdx.y;
        int col;
        bf16_t* outp;
        if (ss < 32) {
            int h = ss, kv = h >> 2, gi = h & 3;
            col  = kv * 768 + gi * 128 + d;
            outp = Q + (((size_t)b * 32 + h) * 2048 + s) * 128 + d;
        } else {
            int kv = ss - 32;
            col  = kv * 768 + 512 + d;
            outp = Kb + (((size_t)b * 8 + kv) * 2048 + s) * 128 + d;
        }
        float x0 = (float)frow[col];
        float x1 = (float)frow[col + 64];
        outp[0]  = (bf16_t)(x0 * c - x1 * sn);
        outp[64] = (bf16_t)(x1 * c + x0 * sn);
    }
}

// ---------------------------------------------------------------- V transpose
__global__ void v_transpose(const bf16_t* __restrict__ fused, bf16_t* __restrict__ Vt) {
    __shared__ bf16_t tile[32][33];
    const int s0 = blockIdx.x * 32;
    const int d0 = blockIdx.y * 32;
    const int bk = blockIdx.z;
    const int b = bk >> 3, kv = bk & 7;
    const int col0 = kv * 768 + 640 + d0;
    const int tx = threadIdx.x, ty = threadIdx.y;
#pragma unroll
    for (int i = 0; i < 4; i++) {
        int sy = ty + i * 8;
        tile[sy][tx] = fused[((size_t)b * 2048 + s0 + sy) * 6144 + col0 + tx];
    }
    __syncthreads();
#pragma unroll
    for (int i = 0; i < 4; i++) {
        int dy = ty + i * 8;
        Vt[((size_t)bk * 128 + d0 + dy) * 2048 + s0 + tx] = tile[tx][dy];
    }
}

// ---------------------------------------------------------------- flash attention v7
// Block = 8 waves = 4 heads x causal pair of q-tiles {p, 63-p}; one shared
// K/V stream (KVBLK=64, double-buffered, 64 KiB LDS). Staging bytes and
// barriers per unit work halve vs fwd6. Short-q waves predicate off tiles
// beyond their diagonal but hit every barrier. ntiles uniform per block.
__global__ __launch_bounds__(512) void attn_fwd7(const bf16_t* __restrict__ Q,
                                                 const bf16_t* __restrict__ Kb,
                                                 const bf16_t* __restrict__ Vt,
                                                 bf16_t* __restrict__ ctx) {
    __shared__ __align__(16) bf16_t Ks[2][64][128];   // [buf][kv][d], byte ^= (kv&7)<<4
    __shared__ __align__(16) bf16_t Vs[2][128][64];   // [buf][d][kv], byte ^= (d&3)<<4
    const int tid  = threadIdx.x;
    const int lane = tid & 63;
    const int wid  = tid >> 6;           // 0..7
    const int l31  = lane & 31;
    const int hi   = lane >> 5;

    const int bid   = blockIdx.x;        // 512 blocks
    const int combo = bid & 15;          // XCD = bid%8 stable -> L2 locality
    const int b     = combo & 1;
    const int kvh   = combo >> 1;
    const int rest  = bid >> 4;          // 0..31
    const int pp    = rest >> 1;         // 0..15
    const int p     = (rest & 1) ? pp : 31 - pp;   // 0..31 (pairs alternate for CU balance)
    const int qa = p, qb = 63 - p;       // qb > qa always
    const int grp = wid >> 2;            // 0: long q-tile, 1: short
    const int qt  = grp ? qa : qb;
    const int q0  = qt * 32;
    const int h   = kvh * 4 + (wid & 3);
    const int ntiles = (qb >> 1) + 1;    // uniform across block

    const bf16_t* kbase = Kb + (((size_t)b * 8 + kvh) * 2048) * 128;
    const bf16_t* vbase = Vt + (((size_t)b * 8 + kvh) * 128) * 2048;
    const float kl = 0.12750062133361622f;      // (1/sqrt(128)) * log2(e)

    // stage one 64-kv tile (K 16KB + V 16KB), 4 async_load16/thread
    auto stageKV = [&](int bufi, int kv0) {
#pragma unroll
        for (int c = 0; c < 2; ++c) {
            int q = tid + 512 * c;                       // 0..1023
            int r = q >> 4;                              // kv row 0..63
            int cl = ((q & 15) * 16) ^ ((r & 7) << 4);   // swizzled byte col
            async_load16(kbase + (size_t)(kv0 + r) * 128 + (cl >> 1),
                         &Ks[bufi][0][0] + q * 8);
        }
#pragma unroll
        for (int c = 0; c < 2; ++c) {
            int q = tid + 512 * c;
            int d = q >> 3;                              // d row 0..127
            int cl = ((q & 7) * 16) ^ ((d & 3) << 4);
            async_load16(vbase + (size_t)d * 2048 + kv0 + (cl >> 1),
                         &Vs[bufi][0][0] + q * 8);
        }
    };

    const bf16_t* qbase = Q + (((size_t)b * 32 + h) * 2048 + q0) * 128;
    bf16x8 qf[8];
#pragma unroll
    for (int kc = 0; kc < 8; ++kc)
        qf[kc] = *(const bf16x8*)(qbase + (size_t)l31 * 128 + kc * 16 + hi * 8);

    f32x16 o[4];
#pragma unroll
    for (int db = 0; db < 4; ++db)
#pragma unroll
        for (int r = 0; r < 16; ++r) o[db][r] = 0.f;
    float m = -1e30f, lsum = 0.f;

    const int kxor = (l31 & 7) << 3;     // elem-space xor for K reads
    const int vxor = (l31 & 3) << 3;     // elem-space xor for V reads

    stageKV(0, 0);
    __syncthreads();

    int buf = 0;
    for (int t = 0; t < ntiles; ++t, buf ^= 1) {
        if (t + 1 < ntiles) stageKV(buf ^ 1, (t + 1) * 64);

#pragma unroll
        for (int sub = 0; sub < 2; ++sub) {
            const int kvg0 = t * 64 + sub * 32;
            if (kvg0 > q0 + 31) continue;       // beyond this wave's causal range

            const bf16_t* krow = &Ks[buf][sub * 32 + l31][0];
            f32x16 s;
#pragma unroll
            for (int r = 0; r < 16; ++r) s[r] = 0.f;
#pragma unroll
            for (int kc = 0; kc < 8; kc += 2) {
                bf16x8 k0 = *(const bf16x8*)(krow + ((kc * 16 + hi * 8) ^ kxor));
                bf16x8 k1 = *(const bf16x8*)(krow + (((kc + 1) * 16 + hi * 8) ^ kxor));
                s = MFMA32(k0, qf[kc], s);
                s = MFMA32(k1, qf[kc + 1], s);
            }

            if (kvg0 + 31 > q0) {               // diagonal tile: causal mask
                const int qg = q0 + l31;
#pragma unroll
                for (int r = 0; r < 16; ++r) {
                    int kvg = kvg0 + (r & 3) + 8 * (r >> 2) + 4 * hi;
                    if (kvg > qg) s[r] = -1e30f;
                }
            }
            float mx01 = fmaxf(s[0], s[1]);
#pragma unroll
            for (int r = 2; r < 16; r += 2) mx01 = fmaxf(mx01, fmaxf(s[r], s[r + 1]));
            float pmax = fmaxf(mx01, __shfl_xor(mx01, 32, 64));
            if (pmax > m + 90.5f) {             // defer-max rescale
                float corr = exp2f((m - pmax) * kl);
                lsum *= corr;
#pragma unroll
                for (int db = 0; db < 4; ++db)
#pragma unroll
                    for (int r = 0; r < 16; ++r) o[db][r] *= corr;
                m = pmax;
            }
            const float mk = m * kl;
            float ps4[4] = {0.f, 0.f, 0.f, 0.f};
#pragma unroll
            for (int r = 0; r < 16; ++r) {
                float e = exp2f(fmaf(s[r], kl, -mk));
                s[r] = e;
                ps4[r & 3] += e;
            }
            lsum += (ps4[0] + ps4[1]) + (ps4[2] + ps4[3]);

#pragma unroll
            for (int ks = 0; ks < 2; ++ks) {
                unsigned u0 = pack2(s[ks * 8 + 0], s[ks * 8 + 1]);
                unsigned u1 = pack2(s[ks * 8 + 2], s[ks * 8 + 3]);
                unsigned u2 = pack2(s[ks * 8 + 4], s[ks * 8 + 5]);
                unsigned u3 = pack2(s[ks * 8 + 6], s[ks * 8 + 7]);
                unsigned t0 = __shfl_xor(u0, 32, 64);
                unsigned t1 = __shfl_xor(u1, 32, 64);
                unsigned t2 = __shfl_xor(u2, 32, 64);
                unsigned t3 = __shfl_xor(u3, 32, 64);
                u32x4 uw;
                uw[0] = hi ? t2 : u0;
                uw[1] = hi ? t3 : u1;
                uw[2] = hi ? u2 : t0;
                uw[3] = hi ? u3 : t1;
                bf16x8 pb = __builtin_bit_cast(bf16x8, uw);
                const int vcol = (sub * 32 + ks * 16 + hi * 8) ^ vxor;
#pragma unroll
                for (int db = 0; db < 4; ++db) {
                    bf16x8 vf = *(const bf16x8*)(&Vs[buf][db * 32 + l31][0] + vcol);
                    o[db] = MFMA32(vf, pb, o[db]);
                }
            }
        }
        __syncthreads();   // drains staging vmcnt + all waves done with buf
    }

    float lall = lsum + __shfl_xor(lsum, 32, 64);
    const float inv = 1.0f / lall;
    bf16_t* cb = ctx + ((size_t)(b * 2048 + q0 + l31)) * 4096 + h * 128;
#pragma unroll
    for (int db = 0; db < 4; ++db)
#pragma unroll
        for (int g = 0; g < 4; ++g) {
            bf16x4 w;
#pragma unroll
            for (int i = 0; i < 4; ++i) w[i] = (bf16_t)(o[db][g * 4 + i] * inv);
            *(bf16x4*)(cb + db * 32 + g * 8 + hi * 4) = w;
        }
}

// ---------------------------------------------------------------- launch
extern "C" void kernel_launch(void* const* d_in, const int* in_sizes, int n_in,
                              void* d_out, int out_size, void* d_ws, size_t ws_size,
                              hipStream_t stream) {
    const float* hs   = (const float*)d_in[0];
    const int*   pos  = (const int*)d_in[1];
    const float* wqkv = (const float*)d_in[2];
    const float* wd   = (const float*)d_in[3];
    float* out = (float*)d_out;
    char* ws = (char*)d_ws;

    bf16_t* Xb    = (bf16_t*)(ws + 0ull);           // later reused as Q
    bf16_t* Wqkvb = (bf16_t*)(ws + 33554432ull);
    bf16_t* Wdb   = (bf16_t*)(ws + 83886080ull);
    bf16_t* fused = (bf16_t*)(ws + 117440512ull);   // later reused as ctx
    bf16_t* Kb    = (bf16_t*)(ws + 167772160ull);
    bf16_t* Vt    = (bf16_t*)(ws + 176160768ull);
    bf16_t* Qb    = Xb;
    bf16_t* ctx   = fused;

    cvt3_f32_to_bf16<<<1792, 256, 0, stream>>>(hs, Xb, 16777216,
                                               wqkv, Wqkvb, 25165824,
                                               wd, Wdb, 16777216);

    gemm_qkv<<<256, 512, 0, stream>>>(Xb, Wqkvb, fused, 4096, 6144, 4096);

    rope_scatter<<<4096, dim3(64, 8), 0, stream>>>(fused, pos, Qb, Kb);
    v_transpose<<<dim3(64, 4, 16), dim3(32, 8), 0, stream>>>(fused, Vt);

    attn_fwd7<<<512, 512, 0, stream>>>(Qb, Kb, Vt, ctx);

    gemm256<float><<<256, 512, 0, stream>>>(ctx, Wdb, out, 4096, 4096, 4096);
}

// Round 15
// 584.668 us; speedup vs baseline: 1.0040x; 1.0040x over previous
//
#include <hip/hip_runtime.h>

typedef __bf16 bf16_t;
typedef __bf16 bf16x8 __attribute__((ext_vector_type(8)));
typedef __bf16 bf16x4 __attribute__((ext_vector_type(4)));
typedef __bf16 bf16x2 __attribute__((ext_vector_type(2)));
typedef float  f32x4  __attribute__((ext_vector_type(4)));
typedef float  f32x16 __attribute__((ext_vector_type(16)));
typedef unsigned int u32x4 __attribute__((ext_vector_type(4)));

#define MFMA16(a, b, c) __builtin_amdgcn_mfma_f32_16x16x32_bf16((a), (b), (c), 0, 0, 0)
#define MFMA32(a, b, c) __builtin_amdgcn_mfma_f32_32x32x16_bf16((a), (b), (c), 0, 0, 0)

__device__ __forceinline__ void async_load16(const void* g, void* l) {
    __builtin_amdgcn_global_load_lds(
        (const __attribute__((address_space(1))) void*)g,
        (__attribute__((address_space(3))) void*)l, 16, 0, 0);
}

__device__ __forceinline__ unsigned pack2(float a, float b) {
    bf16x2 t;
    t[0] = (bf16_t)a;
    t[1] = (bf16_t)b;
    return __builtin_bit_cast(unsigned, t);
}

// ---------------------------------------------------------------- fp32 -> bf16 (3 tensors, one launch)
__global__ void cvt3_f32_to_bf16(const float* __restrict__ s0, bf16_t* __restrict__ d0, int n0,
                                 const float* __restrict__ s1, bf16_t* __restrict__ d1, int n1,
                                 const float* __restrict__ s2, bf16_t* __restrict__ d2, int n2) {
    const float* s; bf16_t* d; int n, bl, nb;
    const int bid = blockIdx.x;
    if (bid < 512)       { s = s0; d = d0; n = n0; bl = bid;        nb = 512; }
    else if (bid < 1280) { s = s1; d = d1; n = n1; bl = bid - 512;  nb = 768; }
    else                 { s = s2; d = d2; n = n2; bl = bid - 1280; nb = 512; }
    const int stride4 = nb * blockDim.x * 4;
    for (int j = (bl * blockDim.x + threadIdx.x) * 4; j < n; j += stride4) {
        float4 v = *(const float4*)(s + j);
        bf16x4 o = { (bf16_t)v.x, (bf16_t)v.y, (bf16_t)v.z, (bf16_t)v.w };
        *(bf16x4*)(d + j) = o;
    }
}

// ---------------------------------------------------------------- QKV GEMM: exact 256-block grid (r13, unchanged)
__global__ __launch_bounds__(512, 2) void gemm_qkv(const bf16_t* __restrict__ A,
                                                   const bf16_t* __restrict__ B,
                                                   bf16_t* __restrict__ C,
                                                   int M, int N, int K) {
    __shared__ __align__(16) bf16_t ldsA[2][256][64];   // 64 KiB
    __shared__ __align__(16) bf16_t ldsB[2][192][64];   // 48 KiB
    const int tid  = threadIdx.x;
    const int lane = tid & 63;
    const int wid  = tid >> 6;
    const int lrow = lane & 15, lhi = lane >> 4;
    const int wrow = (wid >> 1) * 64;
    const int wcol = (wid & 1) * 96;
    const int NT = K >> 6;

    const int nwg = gridDim.x;
    const int w = ((int)blockIdx.x & 7) * (nwg >> 3) + ((int)blockIdx.x >> 3);
    const int nbx = N / 384;
    const size_t m0 = (size_t)(w / nbx) * 256;
    const size_t n0b = (size_t)(w % nbx) * 384;

    const int cm = (((lrow & 1) << 5) | ((lrow & 2) << 3) | ((lrow & 4) << 1));

    const bf16_t* Am = A + m0 * K;

    auto stageA = [&](int bufi, int k0) {
#pragma unroll
        for (int c = 0; c < 4; ++c) {
            int q = tid + 512 * c;
            int row = q >> 3, slot = q & 7;
            int gc = (slot * 8) ^ (((row & 1) << 5) | ((row & 2) << 3) | ((row & 4) << 1));
            async_load16(Am + (size_t)row * K + k0 + gc, &ldsA[bufi][0][0] + q * 8);
        }
    };
    auto stageB = [&](const bf16_t* Bn, int bufi, int k0) {
#pragma unroll
        for (int c = 0; c < 3; ++c) {
            int q = tid + 512 * c;
            int row = q >> 3, slot = q & 7;
            int gc = (slot * 8) ^ (((row & 1) << 5) | ((row & 2) << 3) | ((row & 4) << 1));
            async_load16(Bn + (size_t)row * K + k0 + gc, &ldsB[bufi][0][0] + q * 8);
        }
    };

    for (int half = 0; half < 2; ++half) {
        const bf16_t* Bn = B + (n0b + half * 192) * K;

        f32x4 acc[4][6];
        const f32x4 vz = {0.f, 0.f, 0.f, 0.f};
#pragma unroll
        for (int i = 0; i < 4; ++i)
#pragma unroll
            for (int j = 0; j < 6; ++j) acc[i][j] = vz;

        stageA(0, 0);
        stageB(Bn, 0, 0);
        stageA(1, 64);
        stageB(Bn, 1, 64);
        asm volatile("s_waitcnt vmcnt(7)" ::: "memory");
        __builtin_amdgcn_s_barrier();

        for (int u = 0; u < NT; ++u) {
            const int cur = u & 1;
            __builtin_amdgcn_s_setprio(1);
#pragma unroll
            for (int kk = 0; kk < 2; ++kk) {
                const int cb = kk * 32 + lhi * 8;
                bf16x8 af[4], bfv[6];
#pragma unroll
                for (int i = 0; i < 4; ++i)
                    af[i] = *(const bf16x8*)(&ldsA[cur][wrow + i * 16 + lrow][0] + (cb ^ cm));
#pragma unroll
                for (int j = 0; j < 6; ++j)
                    bfv[j] = *(const bf16x8*)(&ldsB[cur][wcol + j * 16 + lrow][0] + (cb ^ cm));
#pragma unroll
                for (int i = 0; i < 4; ++i)
#pragma unroll
                    for (int j = 0; j < 6; ++j)
                        acc[i][j] = MFMA16(af[i], bfv[j], acc[i][j]);
            }
            __builtin_amdgcn_s_setprio(0);
            __builtin_amdgcn_s_barrier();
            if (u + 2 < NT) {
                stageA(cur, (u + 2) * 64);
                stageB(Bn, cur, (u + 2) * 64);
            }
            if (u == NT - 2)     asm volatile("s_waitcnt vmcnt(0)" ::: "memory");
            else if (u < NT - 2) asm volatile("s_waitcnt vmcnt(7)" ::: "memory");
            __builtin_amdgcn_s_barrier();
        }

#pragma unroll
        for (int i = 0; i < 4; ++i)
#pragma unroll
            for (int j = 0; j < 6; ++j)
#pragma unroll
                for (int r = 0; r < 4; ++r) {
                    size_t row = m0 + wrow + i * 16 + lhi * 4 + r;
                    size_t col = n0b + half * 192 + wcol + j * 16 + lrow;
                    C[row * (size_t)N + col] = (bf16_t)acc[i][j][r];
                }
    }
}

// ---------------------------------------------------------------- dense GEMM: 256x256 tile, no-barrier read->MFMA
// Port of gemm_qkv structure (r13's only schedule win). 8 waves = 4M x 2N of
// 64x128; BK=64; distance-2 prefetch with counted vmcnt(8); exact 256 grid.
__global__ __launch_bounds__(512) void gemm_dense(const bf16_t* __restrict__ A,
                                                  const bf16_t* __restrict__ B,
                                                  float* __restrict__ C,
                                                  int M, int N, int K) {
    __shared__ __align__(16) bf16_t ldsA[2][256][64];   // 64 KiB
    __shared__ __align__(16) bf16_t ldsB[2][256][64];   // 64 KiB
    const int tid  = threadIdx.x;
    const int lane = tid & 63;
    const int wid  = tid >> 6;
    const int lrow = lane & 15, lhi = lane >> 4;
    const int wrow = (wid >> 1) * 64;    // 4 M-waves
    const int wcol = (wid & 1) * 128;    // 2 N-waves
    const int NT = K >> 6;

    const int nwg = gridDim.x;           // 256
    const int w = ((int)blockIdx.x & 7) * (nwg >> 3) + ((int)blockIdx.x >> 3);
    const int nbx = N >> 8;              // 16
    const size_t m0 = (size_t)(w / nbx) * 256;
    const size_t n0 = (size_t)(w % nbx) * 256;

    const int cm = (((lrow & 1) << 5) | ((lrow & 2) << 3) | ((lrow & 4) << 1));

    const bf16_t* Am = A + m0 * K;
    const bf16_t* Bn = B + n0 * K;

    auto stageP = [&](const bf16_t* src, bf16_t* dst, int k0) {
#pragma unroll
        for (int c = 0; c < 4; ++c) {
            int q = tid + 512 * c;       // 0..2047
            int row = q >> 3, slot = q & 7;
            int gc = (slot * 8) ^ (((row & 1) << 5) | ((row & 2) << 3) | ((row & 4) << 1));
            async_load16(src + (size_t)row * K + k0 + gc, dst + q * 8);
        }
    };

    f32x4 acc[4][8];
    const f32x4 vz = {0.f, 0.f, 0.f, 0.f};
#pragma unroll
    for (int i = 0; i < 4; ++i)
#pragma unroll
        for (int j = 0; j < 8; ++j) acc[i][j] = vz;

    stageP(Am, &ldsA[0][0][0], 0);
    stageP(Bn, &ldsB[0][0][0], 0);
    stageP(Am, &ldsA[1][0][0], 64);
    stageP(Bn, &ldsB[1][0][0], 64);
    asm volatile("s_waitcnt vmcnt(8)" ::: "memory");
    __builtin_amdgcn_s_barrier();

    for (int u = 0; u < NT; ++u) {
        const int cur = u & 1;
        __builtin_amdgcn_s_setprio(1);
#pragma unroll
        for (int kk = 0; kk < 2; ++kk) {
            const int cb = kk * 32 + lhi * 8;
            bf16x8 af[4], bfv[8];
#pragma unroll
            for (int i = 0; i < 4; ++i)
                af[i] = *(const bf16x8*)(&ldsA[cur][wrow + i * 16 + lrow][0] + (cb ^ cm));
#pragma unroll
            for (int j = 0; j < 8; ++j)
                bfv[j] = *(const bf16x8*)(&ldsB[cur][wcol + j * 16 + lrow][0] + (cb ^ cm));
            // no explicit lgkm drain: compiler inserts fine-grained waits
#pragma unroll
            for (int i = 0; i < 4; ++i)
#pragma unroll
                for (int j = 0; j < 8; ++j)
                    acc[i][j] = MFMA16(af[i], bfv[j], acc[i][j]);
        }
        __builtin_amdgcn_s_setprio(0);
        __builtin_amdgcn_s_barrier();
        if (u + 2 < NT) {
            stageP(Am, &ldsA[cur][0][0], (u + 2) * 64);
            stageP(Bn, &ldsB[cur][0][0], (u + 2) * 64);
        }
        if (u == NT - 2)     asm volatile("s_waitcnt vmcnt(0)" ::: "memory");
        else if (u < NT - 2) asm volatile("s_waitcnt vmcnt(8)" ::: "memory");
        __builtin_amdgcn_s_barrier();
    }

#pragma unroll
    for (int i = 0; i < 4; ++i)
#pragma unroll
        for (int j = 0; j < 8; ++j)
#pragma unroll
            for (int r = 0; r < 4; ++r) {
                size_t row = m0 + wrow + i * 16 + lhi * 4 + r;
                size_t col = n0 + wcol + j * 16 + lrow;
                C[row * (size_t)N + col] = acc[i][j][r];
            }
}

// ---------------------------------------------------------------- fused RoPE-scatter + V-transpose
// bid < 4096: RoPE for token bid (256 thr = 64 d x 4 slots, 10 iters).
// bid >= 4096: V-transpose tile (256 thr = 32 x 8), flattened (s0, d0, bk).
__global__ void rope_vt(const bf16_t* __restrict__ fused, const int* __restrict__ pos_ids,
                        bf16_t* __restrict__ Q, bf16_t* __restrict__ Kb,
                        bf16_t* __restrict__ Vt) {
    __shared__ bf16_t tile[32][33];
    const int bid = blockIdx.x;
    if (bid < 4096) {
        const int token = bid;
        const int b = token >> 11, s = token & 2047;
        const int d = threadIdx.x & 63;
        const int y = threadIdx.x >> 6;          // 0..3
        const float pos = (float)pos_ids[token];
        const float inv = __expf(-(float)d * (9.210340371976184f / 64.0f));
        float sn, c;
        sincosf(pos * inv, &sn, &c);
        const bf16_t* frow = fused + (size_t)token * 6144;
        for (int it = 0; it < 10; ++it) {
            int ss = it * 4 + y;                 // 0..39
            int col;
            bf16_t* outp;
            if (ss < 32) {
                int h = ss, kv = h >> 2, gi = h & 3;
                col  = kv * 768 + gi * 128 + d;
                outp = Q + (((size_t)b * 32 + h) * 2048 + s) * 128 + d;
            } else {
                int kv = ss - 32;
                col  = kv * 768 + 512 + d;
                outp = Kb + (((size_t)b * 8 + kv) * 2048 + s) * 128 + d;
            }
            float x0 = (float)frow[col];
            float x1 = (float)frow[col + 64];
            outp[0]  = (bf16_t)(x0 * c - x1 * sn);
            outp[64] = (bf16_t)(x1 * c + x0 * sn);
        }
    } else {
        const int idx = bid - 4096;              // 64 * 4 * 16
        const int s0 = (idx & 63) * 32;
        const int d0 = ((idx >> 6) & 3) * 32;
        const int bk = idx >> 8;                 // 0..15
        const int b = bk >> 3, kv = bk & 7;
        const int col0 = kv * 768 + 640 + d0;
        const int tx = threadIdx.x & 31, ty = threadIdx.x >> 5;
#pragma unroll
        for (int i = 0; i < 4; i++) {
            int sy = ty + i * 8;
            tile[sy][tx] = fused[((size_t)b * 2048 + s0 + sy) * 6144 + col0 + tx];
        }
        __syncthreads();
#pragma unroll
        for (int i = 0; i < 4; i++) {
            int dy = ty + i * 8;
            Vt[((size_t)bk * 128 + d0 + dy) * 2048 + s0 + tx] = tile[tx][dy];
        }
    }
}

// ---------------------------------------------------------------- flash attention v6 (r13 proven version)
__global__ __launch_bounds__(256) void attn_fwd6(const bf16_t* __restrict__ Q,
                                                 const bf16_t* __restrict__ Kb,
                                                 const bf16_t* __restrict__ Vt,
                                                 bf16_t* __restrict__ ctx) {
    __shared__ __align__(16) bf16_t Ks[2][32][128];
    __shared__ __align__(16) bf16_t Vs[2][128][32];
    const int tid  = threadIdx.x;
    const int lane = tid & 63;
    const int wid  = tid >> 6;
    const int l31  = lane & 31;
    const int hi   = lane >> 5;

    const int bidx  = blockIdx.x;
    const int slot  = bidx >> 8;
    const int rr    = (bidx >> 4) & 15;
    const int combo = bidx & 15;
    const int b     = combo & 1;
    const int kvh   = combo >> 1;
    int qt;
    switch (slot) {
        case 0: qt = rr;      break;
        case 1: qt = 63 - rr; break;
        case 2: qt = 16 + rr; break;
        default: qt = 47 - rr; break;
    }
    const int q0 = qt * 32;
    const int h  = kvh * 4 + wid;

    const bf16_t* kbase = Kb + (((size_t)b * 8 + kvh) * 2048) * 128;
    const bf16_t* vbase = Vt + (((size_t)b * 8 + kvh) * 128) * 2048;
    const float kl = 0.12750062133361622f;

    auto stageKV = [&](int bufi, int kv0) {
#pragma unroll
        for (int c = 0; c < 2; ++c) {
            int q = tid + 256 * c;
            int r = q >> 4;
            int cl = ((q & 15) * 16) ^ ((r & 7) << 4);
            async_load16(kbase + (size_t)(kv0 + r) * 128 + (cl >> 1),
                         &Ks[bufi][0][0] + q * 8);
        }
#pragma unroll
        for (int c = 0; c < 2; ++c) {
            int q = tid + 256 * c;
            int d = q >> 2;
            int cl = ((q & 3) * 16) ^ ((d & 3) << 4);
            async_load16(vbase + (size_t)d * 2048 + kv0 + (cl >> 1),
                         &Vs[bufi][0][0] + q * 8);
        }
    };

    const bf16_t* qbase = Q + (((size_t)b * 32 + h) * 2048 + q0) * 128;
    bf16x8 qf[8];
#pragma unroll
    for (int kc = 0; kc < 8; ++kc)
        qf[kc] = *(const bf16x8*)(qbase + (size_t)l31 * 128 + kc * 16 + hi * 8);

    f32x16 o[4];
#pragma unroll
    for (int db = 0; db < 4; ++db)
#pragma unroll
        for (int r = 0; r < 16; ++r) o[db][r] = 0.f;
    float m = -1e30f, lsum = 0.f;

    const int kxor = (l31 & 7) << 3;
    const int vxor = (l31 & 3) << 3;

    stageKV(0, 0);
    __syncthreads();

    int buf = 0;
    for (int st = 0; st <= qt; ++st, buf ^= 1) {
        if (st < qt) stageKV(buf ^ 1, (st + 1) * 32);

        const bf16_t* krow = &Ks[buf][l31][0];
        f32x16 s;
#pragma unroll
        for (int r = 0; r < 16; ++r) s[r] = 0.f;
#pragma unroll
        for (int kc = 0; kc < 8; kc += 2) {
            bf16x8 k0 = *(const bf16x8*)(krow + ((kc * 16 + hi * 8) ^ kxor));
            bf16x8 k1 = *(const bf16x8*)(krow + (((kc + 1) * 16 + hi * 8) ^ kxor));
            s = MFMA32(k0, qf[kc], s);
            s = MFMA32(k1, qf[kc + 1], s);
        }

        if (st == qt) {
            const int qg = q0 + l31;
            const int kv0 = st * 32;
#pragma unroll
            for (int r = 0; r < 16; ++r) {
                int kvg = kv0 + (r & 3) + 8 * (r >> 2) + 4 * hi;
                if (kvg > qg) s[r] = -1e30f;
            }
        }
        float mx01 = fmaxf(s[0], s[1]);
#pragma unroll
        for (int r = 2; r < 16; r += 2) mx01 = fmaxf(mx01, fmaxf(s[r], s[r + 1]));
        float pmax = fmaxf(mx01, __shfl_xor(mx01, 32, 64));
        if (pmax > m + 90.5f) {
            float corr = exp2f((m - pmax) * kl);
            lsum *= corr;
#pragma unroll
            for (int db = 0; db < 4; ++db)
#pragma unroll
                for (int r = 0; r < 16; ++r) o[db][r] *= corr;
            m = pmax;
        }
        const float mk = m * kl;
        float ps4[4] = {0.f, 0.f, 0.f, 0.f};
#pragma unroll
        for (int r = 0; r < 16; ++r) {
            float e = exp2f(fmaf(s[r], kl, -mk));
            s[r] = e;
            ps4[r & 3] += e;
        }
        lsum += (ps4[0] + ps4[1]) + (ps4[2] + ps4[3]);

#pragma unroll
        for (int ks = 0; ks < 2; ++ks) {
            unsigned u0 = pack2(s[ks * 8 + 0], s[ks * 8 + 1]);
            unsigned u1 = pack2(s[ks * 8 + 2], s[ks * 8 + 3]);
            unsigned u2 = pack2(s[ks * 8 + 4], s[ks * 8 + 5]);
            unsigned u3 = pack2(s[ks * 8 + 6], s[ks * 8 + 7]);
            unsigned t0 = __shfl_xor(u0, 32, 64);
            unsigned t1 = __shfl_xor(u1, 32, 64);
            unsigned t2 = __shfl_xor(u2, 32, 64);
            unsigned t3 = __shfl_xor(u3, 32, 64);
            u32x4 uw;
            uw[0] = hi ? t2 : u0;
            uw[1] = hi ? t3 : u1;
            uw[2] = hi ? u2 : t0;
            uw[3] = hi ? u3 : t1;
            bf16x8 pb = __builtin_bit_cast(bf16x8, uw);
            const int vcol = (ks * 16 + hi * 8) ^ vxor;
#pragma unroll
            for (int db = 0; db < 4; ++db) {
                bf16x8 vf = *(const bf16x8*)(&Vs[buf][db * 32 + l31][0] + vcol);
                o[db] = MFMA32(vf, pb, o[db]);
            }
        }
        __syncthreads();
    }

    float lall = lsum + __shfl_xor(lsum, 32, 64);
    const float inv = 1.0f / lall;
    bf16_t* cb = ctx + ((size_t)(b * 2048 + q0 + l31)) * 4096 + h * 128;
#pragma unroll
    for (int db = 0; db < 4; ++db)
#pragma unroll
        for (int g = 0; g < 4; ++g) {
            bf16x4 w;
#pragma unroll
            for (int i = 0; i < 4; ++i) w[i] = (bf16_t)(o[db][g * 4 + i] * inv);
            *(bf16x4*)(cb + db * 32 + g * 8 + hi * 4) = w;
        }
}

// ---------------------------------------------------------------- launch
extern "C" void kernel_launch(void* const* d_in, const int* in_sizes, int n_in,
                              void* d_out, int out_size, void* d_ws, size_t ws_size,
                              hipStream_t stream) {
    const float* hs   = (const float*)d_in[0];
    const int*   pos  = (const int*)d_in[1];
    const float* wqkv = (const float*)d_in[2];
    const float* wd   = (const float*)d_in[3];
    float* out = (float*)d_out;
    char* ws = (char*)d_ws;

    bf16_t* Xb    = (bf16_t*)(ws + 0ull);           // later reused as Q
    bf16_t* Wqkvb = (bf16_t*)(ws + 33554432ull);
    bf16_t* Wdb   = (bf16_t*)(ws + 83886080ull);
    bf16_t* fused = (bf16_t*)(ws + 117440512ull);   // later reused as ctx
    bf16_t* Kb    = (bf16_t*)(ws + 167772160ull);
    bf16_t* Vt    = (bf16_t*)(ws + 176160768ull);
    bf16_t* Qb    = Xb;
    bf16_t* ctx   = fused;

    cvt3_f32_to_bf16<<<1792, 256, 0, stream>>>(hs, Xb, 16777216,
                                               wqkv, Wqkvb, 25165824,
                                               wd, Wdb, 16777216);

    gemm_qkv<<<256, 512, 0, stream>>>(Xb, Wqkvb, fused, 4096, 6144, 4096);

    rope_vt<<<8192, 256, 0, stream>>>(fused, pos, Qb, Kb, Vt);

    attn_fwd6<<<1024, 256, 0, stream>>>(Qb, Kb, Vt, ctx);

    gemm_dense<<<256, 512, 0, stream>>>(ctx, Wdb, out, 4096, 4096, 4096);
}

// Round 16
// 576.210 us; speedup vs baseline: 1.0187x; 1.0147x over previous
//
#include <hip/hip_runtime.h>

typedef __bf16 bf16_t;
typedef __bf16 bf16x8 __attribute__((ext_vector_type(8)));
typedef __bf16 bf16x4 __attribute__((ext_vector_type(4)));
typedef __bf16 bf16x2 __attribute__((ext_vector_type(2)));
typedef float  f32x4  __attribute__((ext_vector_type(4)));
typedef float  f32x16 __attribute__((ext_vector_type(16)));
typedef unsigned int u32x4 __attribute__((ext_vector_type(4)));

#define MFMA16(a, b, c) __builtin_amdgcn_mfma_f32_16x16x32_bf16((a), (b), (c), 0, 0, 0)
#define MFMA32(a, b, c) __builtin_amdgcn_mfma_f32_32x32x16_bf16((a), (b), (c), 0, 0, 0)

__device__ __forceinline__ void async_load16(const void* g, void* l) {
    __builtin_amdgcn_global_load_lds(
        (const __attribute__((address_space(1))) void*)g,
        (__attribute__((address_space(3))) void*)l, 16, 0, 0);
}

__device__ __forceinline__ unsigned pack2(float a, float b) {
    bf16x2 t;
    t[0] = (bf16_t)a;
    t[1] = (bf16_t)b;
    return __builtin_bit_cast(unsigned, t);
}

// ---------------------------------------------------------------- fp32 -> bf16 (3 tensors, one launch)
__global__ void cvt3_f32_to_bf16(const float* __restrict__ s0, bf16_t* __restrict__ d0, int n0,
                                 const float* __restrict__ s1, bf16_t* __restrict__ d1, int n1,
                                 const float* __restrict__ s2, bf16_t* __restrict__ d2, int n2) {
    const float* s; bf16_t* d; int n, bl, nb;
    const int bid = blockIdx.x;
    if (bid < 512)       { s = s0; d = d0; n = n0; bl = bid;        nb = 512; }
    else if (bid < 1280) { s = s1; d = d1; n = n1; bl = bid - 512;  nb = 768; }
    else                 { s = s2; d = d2; n = n2; bl = bid - 1280; nb = 512; }
    const int stride4 = nb * blockDim.x * 4;
    for (int j = (bl * blockDim.x + threadIdx.x) * 4; j < n; j += stride4) {
        float4 v = *(const float4*)(s + j);
        bf16x4 o = { (bf16_t)v.x, (bf16_t)v.y, (bf16_t)v.z, (bf16_t)v.w };
        *(bf16x4*)(d + j) = o;
    }
}

__device__ __forceinline__ void storeC(float* C, size_t idx, float v)  { C[idx] = v; }
__device__ __forceinline__ void storeC(bf16_t* C, size_t idx, float v) { C[idx] = (bf16_t)v; }

// ---------------------------------------------------------------- QKV GEMM: exact 256-block grid (r13)
// XCD mapping: each XCD gets a 4x8 RECTANGLE of the 16x16 tile grid
// (4 A-panels + 8 B-panels = 32 MB/XCD working set, vs 2x16 rows = 52 MB).
__global__ __launch_bounds__(512, 2) void gemm_qkv(const bf16_t* __restrict__ A,
                                                   const bf16_t* __restrict__ B,
                                                   bf16_t* __restrict__ C,
                                                   int M, int N, int K) {
    __shared__ __align__(16) bf16_t ldsA[2][256][64];   // 64 KiB
    __shared__ __align__(16) bf16_t ldsB[2][192][64];   // 48 KiB
    const int tid  = threadIdx.x;
    const int lane = tid & 63;
    const int wid  = tid >> 6;
    const int lrow = lane & 15, lhi = lane >> 4;
    const int wrow = (wid >> 1) * 64;
    const int wcol = (wid & 1) * 96;
    const int NT = K >> 6;

    // 4x8 rectangle per XCD (grid fixed at 256 = 16 rows x 16 cols)
    const int xcd = (int)blockIdx.x & 7;
    const int idx = (int)blockIdx.x >> 3;          // 0..31
    const int rowt = (xcd >> 1) * 4 + (idx >> 3);  // 0..15
    const int colt = (xcd & 1) * 8 + (idx & 7);    // 0..15
    const size_t m0  = (size_t)rowt * 256;
    const size_t n0b = (size_t)colt * 384;

    const int cm = (((lrow & 1) << 5) | ((lrow & 2) << 3) | ((lrow & 4) << 1));

    const bf16_t* Am = A + m0 * K;

    auto stageA = [&](int bufi, int k0) {
#pragma unroll
        for (int c = 0; c < 4; ++c) {
            int q = tid + 512 * c;
            int row = q >> 3, slot = q & 7;
            int gc = (slot * 8) ^ (((row & 1) << 5) | ((row & 2) << 3) | ((row & 4) << 1));
            async_load16(Am + (size_t)row * K + k0 + gc, &ldsA[bufi][0][0] + q * 8);
        }
    };
    auto stageB = [&](const bf16_t* Bn, int bufi, int k0) {
#pragma unroll
        for (int c = 0; c < 3; ++c) {
            int q = tid + 512 * c;
            int row = q >> 3, slot = q & 7;
            int gc = (slot * 8) ^ (((row & 1) << 5) | ((row & 2) << 3) | ((row & 4) << 1));
            async_load16(Bn + (size_t)row * K + k0 + gc, &ldsB[bufi][0][0] + q * 8);
        }
    };

    for (int half = 0; half < 2; ++half) {
        const bf16_t* Bn = B + (n0b + half * 192) * K;

        f32x4 acc[4][6];
        const f32x4 vz = {0.f, 0.f, 0.f, 0.f};
#pragma unroll
        for (int i = 0; i < 4; ++i)
#pragma unroll
            for (int j = 0; j < 6; ++j) acc[i][j] = vz;

        stageA(0, 0);
        stageB(Bn, 0, 0);
        stageA(1, 64);
        stageB(Bn, 1, 64);
        asm volatile("s_waitcnt vmcnt(7)" ::: "memory");
        __builtin_amdgcn_s_barrier();

        for (int u = 0; u < NT; ++u) {
            const int cur = u & 1;
            __builtin_amdgcn_s_setprio(1);
#pragma unroll
            for (int kk = 0; kk < 2; ++kk) {
                const int cb = kk * 32 + lhi * 8;
                bf16x8 af[4], bfv[6];
#pragma unroll
                for (int i = 0; i < 4; ++i)
                    af[i] = *(const bf16x8*)(&ldsA[cur][wrow + i * 16 + lrow][0] + (cb ^ cm));
#pragma unroll
                for (int j = 0; j < 6; ++j)
                    bfv[j] = *(const bf16x8*)(&ldsB[cur][wcol + j * 16 + lrow][0] + (cb ^ cm));
#pragma unroll
                for (int i = 0; i < 4; ++i)
#pragma unroll
                    for (int j = 0; j < 6; ++j)
                        acc[i][j] = MFMA16(af[i], bfv[j], acc[i][j]);
            }
            __builtin_amdgcn_s_setprio(0);
            __builtin_amdgcn_s_barrier();
            if (u + 2 < NT) {
                stageA(cur, (u + 2) * 64);
                stageB(Bn, cur, (u + 2) * 64);
            }
            if (u == NT - 2)     asm volatile("s_waitcnt vmcnt(0)" ::: "memory");
            else if (u < NT - 2) asm volatile("s_waitcnt vmcnt(7)" ::: "memory");
            __builtin_amdgcn_s_barrier();
        }

#pragma unroll
        for (int i = 0; i < 4; ++i)
#pragma unroll
            for (int j = 0; j < 6; ++j)
#pragma unroll
                for (int r = 0; r < 4; ++r) {
                    size_t row = m0 + wrow + i * 16 + lhi * 4 + r;
                    size_t col = n0b + half * 192 + wcol + j * 16 + lrow;
                    C[row * (size_t)N + col] = (bf16_t)acc[i][j][r];
                }
    }
}

// ---------------------------------------------------------------- 256x256 GEMM (B^T), BK=64 (dense; r13-proven)
template <typename OT>
__global__ __launch_bounds__(512, 2) void gemm256(const bf16_t* __restrict__ A,
                                                  const bf16_t* __restrict__ B,
                                                  OT* __restrict__ C,
                                                  int M, int N, int K) {
    __shared__ __align__(16) bf16_t lds[2][2][2][128][64];
    const int tid  = threadIdx.x;
    const int lane = tid & 63;
    const int wid  = tid >> 6;
    const int lrow = lane & 15, lhi = lane >> 4;
    const int wrow = (wid >> 2) * 64;
    const int wcol = (wid & 3) * 32;
    const int NT = K >> 6;
    const int nbx = N >> 8;

    const int nwg = gridDim.x;
    const int w = ((int)blockIdx.x & 7) * (nwg >> 3) + ((int)blockIdx.x >> 3);
    const size_t m0 = (size_t)(w / nbx) * 256;
    const size_t n0 = (size_t)(w % nbx) * 256;

    const int cmask = ((lrow & 1) << 5) | ((lrow & 2) << 3) | ((lrow & 4) << 1);
    const int cK0 = (lhi * 8) ^ cmask;
    const int cK1 = (32 + lhi * 8) ^ cmask;
    const int r8 = lane >> 3;
    const int gcol = ((lane & 7) * 8) ^ (((r8 & 1) << 5) | ((r8 & 2) << 3) | ((r8 & 4) << 1));

    auto stage = [&](const bf16_t* srcBase, bf16_t* region) {
#pragma unroll
        for (int c = 0; c < 2; ++c)
            async_load16(srcBase + (size_t)(c * 64 + wid * 8 + r8) * K + gcol,
                         region + c * 4096 + wid * 512);
    };

    int buf = 0;
    bf16x8 af[2][4];
    bf16x8 b0f[2][2], b1f[2][2];

    auto loadA = [&](int mh) {
#pragma unroll
        for (int i = 0; i < 4; ++i) {
            const bf16_t* rp = &lds[buf][0][mh][wrow + i * 16 + lrow][0];
            af[0][i] = *(const bf16x8*)(rp + cK0);
            af[1][i] = *(const bf16x8*)(rp + cK1);
        }
    };
    auto loadB = [&](int nh, bf16x8 (&bf)[2][2]) {
#pragma unroll
        for (int j = 0; j < 2; ++j) {
            const bf16_t* rp = &lds[buf][1][nh][wcol + j * 16 + lrow][0];
            bf[0][j] = *(const bf16x8*)(rp + cK0);
            bf[1][j] = *(const bf16x8*)(rp + cK1);
        }
    };
    auto mmacc = [&](f32x4 (&acc)[4][2], bf16x8 (&bf)[2][2]) {
#pragma unroll
        for (int kk = 0; kk < 2; ++kk)
#pragma unroll
            for (int i = 0; i < 4; ++i)
#pragma unroll
                for (int j = 0; j < 2; ++j)
                    acc[i][j] = MFMA16(af[kk][i], bf[kk][j], acc[i][j]);
    };

    f32x4 a00[4][2], a01[4][2], a10[4][2], a11[4][2];
    const f32x4 vz = {0.f, 0.f, 0.f, 0.f};
#pragma unroll
    for (int i = 0; i < 4; ++i)
#pragma unroll
        for (int j = 0; j < 2; ++j) { a00[i][j] = vz; a01[i][j] = vz; a10[i][j] = vz; a11[i][j] = vz; }

    const bf16_t* Am = A + m0 * K;
    const bf16_t* Bn = B + n0 * K;

    stage(Am,                     &lds[0][0][0][0][0]);
    stage(Bn,                     &lds[0][1][0][0][0]);
    stage(Bn + (size_t)128 * K,   &lds[0][1][1][0][0]);
    stage(Am + (size_t)128 * K,   &lds[0][0][1][0][0]);
    stage(Am + 64,                &lds[1][0][0][0][0]);
    stage(Bn + 64,                &lds[1][1][0][0][0]);
    asm volatile("s_waitcnt vmcnt(4)" ::: "memory");
    __builtin_amdgcn_s_barrier();

    for (int u = 0; u < NT; ++u, buf ^= 1) {
        loadA(0);
        loadB(0, b0f);
        loadB(1, b1f);
        __builtin_amdgcn_s_barrier();
        asm volatile("s_waitcnt lgkmcnt(0)" ::: "memory");
        if (u + 1 < NT) {
            stage(Bn + (size_t)(u + 1) * 64 + (size_t)128 * K, &lds[buf ^ 1][1][1][0][0]);
            stage(Am + (size_t)(u + 1) * 64 + (size_t)128 * K, &lds[buf ^ 1][0][1][0][0]);
        }
        __builtin_amdgcn_s_setprio(1);
        mmacc(a00, b0f);
        mmacc(a01, b1f);
        __builtin_amdgcn_s_setprio(0);
        __builtin_amdgcn_s_barrier();
        loadA(1);
        __builtin_amdgcn_s_barrier();
        asm volatile("s_waitcnt lgkmcnt(0)" ::: "memory");
        if (u + 2 < NT) {
            stage(Am + (size_t)(u + 2) * 64, &lds[buf][0][0][0][0]);
            stage(Bn + (size_t)(u + 2) * 64, &lds[buf][1][0][0][0]);
        }
        __builtin_amdgcn_s_setprio(1);
        mmacc(a10, b0f);
        mmacc(a11, b1f);
        __builtin_amdgcn_s_setprio(0);
        if (u == NT - 2)     asm volatile("s_waitcnt vmcnt(0)" ::: "memory");
        else if (u < NT - 2) asm volatile("s_waitcnt vmcnt(4)" ::: "memory");
        __builtin_amdgcn_s_barrier();
    }

    auto storeQ = [&](f32x4 (&acc)[4][2], int mq, int nq) {
#pragma unroll
        for (int i = 0; i < 4; ++i)
#pragma unroll
            for (int j = 0; j < 2; ++j)
#pragma unroll
                for (int r = 0; r < 4; ++r) {
                    size_t row = m0 + mq * 128 + wrow + i * 16 + lhi * 4 + r;
                    size_t col = n0 + nq * 128 + wcol + j * 16 + lrow;
                    storeC(C, row * (size_t)N + col, acc[i][j][r]);
                }
    };
    storeQ(a00, 0, 0); storeQ(a01, 0, 1); storeQ(a10, 1, 0); storeQ(a11, 1, 1);
}

// ---------------------------------------------------------------- fused RoPE-scatter + V-transpose
__global__ void rope_vt(const bf16_t* __restrict__ fused, const int* __restrict__ pos_ids,
                        bf16_t* __restrict__ Q, bf16_t* __restrict__ Kb,
                        bf16_t* __restrict__ Vt) {
    __shared__ bf16_t tile[32][33];
    const int bid = blockIdx.x;
    if (bid < 4096) {
        const int token = bid;
        const int b = token >> 11, s = token & 2047;
        const int d = threadIdx.x & 63;
        const int y = threadIdx.x >> 6;
        const float pos = (float)pos_ids[token];
        const float inv = __expf(-(float)d * (9.210340371976184f / 64.0f));
        float sn, c;
        sincosf(pos * inv, &sn, &c);
        const bf16_t* frow = fused + (size_t)token * 6144;
        for (int it = 0; it < 10; ++it) {
            int ss = it * 4 + y;
            int col;
            bf16_t* outp;
            if (ss < 32) {
                int h = ss, kv = h >> 2, gi = h & 3;
                col  = kv * 768 + gi * 128 + d;
                outp = Q + (((size_t)b * 32 + h) * 2048 + s) * 128 + d;
            } else {
                int kv = ss - 32;
                col  = kv * 768 + 512 + d;
                outp = Kb + (((size_t)b * 8 + kv) * 2048 + s) * 128 + d;
            }
            float x0 = (float)frow[col];
            float x1 = (float)frow[col + 64];
            outp[0]  = (bf16_t)(x0 * c - x1 * sn);
            outp[64] = (bf16_t)(x1 * c + x0 * sn);
        }
    } else {
        const int idx = bid - 4096;
        const int s0 = (idx & 63) * 32;
        const int d0 = ((idx >> 6) & 3) * 32;
        const int bk = idx >> 8;
        const int b = bk >> 3, kv = bk & 7;
        const int col0 = kv * 768 + 640 + d0;
        const int tx = threadIdx.x & 31, ty = threadIdx.x >> 5;
#pragma unroll
        for (int i = 0; i < 4; i++) {
            int sy = ty + i * 8;
            tile[sy][tx] = fused[((size_t)b * 2048 + s0 + sy) * 6144 + col0 + tx];
        }
        __syncthreads();
#pragma unroll
        for (int i = 0; i < 4; i++) {
            int dy = ty + i * 8;
            Vt[((size_t)bk * 128 + d0 + dy) * 2048 + s0 + tx] = tile[tx][dy];
        }
    }
}

// ---------------------------------------------------------------- flash attention v6 (proven)
__global__ __launch_bounds__(256) void attn_fwd6(const bf16_t* __restrict__ Q,
                                                 const bf16_t* __restrict__ Kb,
                                                 const bf16_t* __restrict__ Vt,
                                                 bf16_t* __restrict__ ctx) {
    __shared__ __align__(16) bf16_t Ks[2][32][128];
    __shared__ __align__(16) bf16_t Vs[2][128][32];
    const int tid  = threadIdx.x;
    const int lane = tid & 63;
    const int wid  = tid >> 6;
    const int l31  = lane & 31;
    const int hi   = lane >> 5;

    const int bidx  = blockIdx.x;
    const int slot  = bidx >> 8;
    const int rr    = (bidx >> 4) & 15;
    const int combo = bidx & 15;
    const int b     = combo & 1;
    const int kvh   = combo >> 1;
    int qt;
    switch (slot) {
        case 0: qt = rr;      break;
        case 1: qt = 63 - rr; break;
        case 2: qt = 16 + rr; break;
        default: qt = 47 - rr; break;
    }
    const int q0 = qt * 32;
    const int h  = kvh * 4 + wid;

    const bf16_t* kbase = Kb + (((size_t)b * 8 + kvh) * 2048) * 128;
    const bf16_t* vbase = Vt + (((size_t)b * 8 + kvh) * 128) * 2048;
    const float kl = 0.12750062133361622f;

    auto stageKV = [&](int bufi, int kv0) {
#pragma unroll
        for (int c = 0; c < 2; ++c) {
            int q = tid + 256 * c;
            int r = q >> 4;
            int cl = ((q & 15) * 16) ^ ((r & 7) << 4);
            async_load16(kbase + (size_t)(kv0 + r) * 128 + (cl >> 1),
                         &Ks[bufi][0][0] + q * 8);
        }
#pragma unroll
        for (int c = 0; c < 2; ++c) {
            int q = tid + 256 * c;
            int d = q >> 2;
            int cl = ((q & 3) * 16) ^ ((d & 3) << 4);
            async_load16(vbase + (size_t)d * 2048 + kv0 + (cl >> 1),
                         &Vs[bufi][0][0] + q * 8);
        }
    };

    const bf16_t* qbase = Q + (((size_t)b * 32 + h) * 2048 + q0) * 128;
    bf16x8 qf[8];
#pragma unroll
    for (int kc = 0; kc < 8; ++kc)
        qf[kc] = *(const bf16x8*)(qbase + (size_t)l31 * 128 + kc * 16 + hi * 8);

    f32x16 o[4];
#pragma unroll
    for (int db = 0; db < 4; ++db)
#pragma unroll
        for (int r = 0; r < 16; ++r) o[db][r] = 0.f;
    float m = -1e30f, lsum = 0.f;

    const int kxor = (l31 & 7) << 3;
    const int vxor = (l31 & 3) << 3;

    stageKV(0, 0);
    __syncthreads();

    int buf = 0;
    for (int st = 0; st <= qt; ++st, buf ^= 1) {
        if (st < qt) stageKV(buf ^ 1, (st + 1) * 32);

        const bf16_t* krow = &Ks[buf][l31][0];
        f32x16 s;
#pragma unroll
        for (int r = 0; r < 16; ++r) s[r] = 0.f;
#pragma unroll
        for (int kc = 0; kc < 8; kc += 2) {
            bf16x8 k0 = *(const bf16x8*)(krow + ((kc * 16 + hi * 8) ^ kxor));
            bf16x8 k1 = *(const bf16x8*)(krow + (((kc + 1) * 16 + hi * 8) ^ kxor));
            s = MFMA32(k0, qf[kc], s);
            s = MFMA32(k1, qf[kc + 1], s);
        }

        if (st == qt) {
            const int qg = q0 + l31;
            const int kv0 = st * 32;
#pragma unroll
            for (int r = 0; r < 16; ++r) {
                int kvg = kv0 + (r & 3) + 8 * (r >> 2) + 4 * hi;
                if (kvg > qg) s[r] = -1e30f;
            }
        }
        float mx01 = fmaxf(s[0], s[1]);
#pragma unroll
        for (int r = 2; r < 16; r += 2) mx01 = fmaxf(mx01, fmaxf(s[r], s[r + 1]));
        float pmax = fmaxf(mx01, __shfl_xor(mx01, 32, 64));
        if (pmax > m + 90.5f) {
            float corr = exp2f((m - pmax) * kl);
            lsum *= corr;
#pragma unroll
            for (int db = 0; db < 4; ++db)
#pragma unroll
                for (int r = 0; r < 16; ++r) o[db][r] *= corr;
            m = pmax;
        }
        const float mk = m * kl;
        float ps4[4] = {0.f, 0.f, 0.f, 0.f};
#pragma unroll
        for (int r = 0; r < 16; ++r) {
            float e = exp2f(fmaf(s[r], kl, -mk));
            s[r] = e;
            ps4[r & 3] += e;
        }
        lsum += (ps4[0] + ps4[1]) + (ps4[2] + ps4[3]);

#pragma unroll
        for (int ks = 0; ks < 2; ++ks) {
            unsigned u0 = pack2(s[ks * 8 + 0], s[ks * 8 + 1]);
            unsigned u1 = pack2(s[ks * 8 + 2], s[ks * 8 + 3]);
            unsigned u2 = pack2(s[ks * 8 + 4], s[ks * 8 + 5]);
            unsigned u3 = pack2(s[ks * 8 + 6], s[ks * 8 + 7]);
            unsigned t0 = __shfl_xor(u0, 32, 64);
            unsigned t1 = __shfl_xor(u1, 32, 64);
            unsigned t2 = __shfl_xor(u2, 32, 64);
            unsigned t3 = __shfl_xor(u3, 32, 64);
            u32x4 uw;
            uw[0] = hi ? t2 : u0;
            uw[1] = hi ? t3 : u1;
            uw[2] = hi ? u2 : t0;
            uw[3] = hi ? u3 : t1;
            bf16x8 pb = __builtin_bit_cast(bf16x8, uw);
            const int vcol = (ks * 16 + hi * 8) ^ vxor;
#pragma unroll
            for (int db = 0; db < 4; ++db) {
                bf16x8 vf = *(const bf16x8*)(&Vs[buf][db * 32 + l31][0] + vcol);
                o[db] = MFMA32(vf, pb, o[db]);
            }
        }
        __syncthreads();
    }

    float lall = lsum + __shfl_xor(lsum, 32, 64);
    const float inv = 1.0f / lall;
    bf16_t* cb = ctx + ((size_t)(b * 2048 + q0 + l31)) * 4096 + h * 128;
#pragma unroll
    for (int db = 0; db < 4; ++db)
#pragma unroll
        for (int g = 0; g < 4; ++g) {
            bf16x4 w;
#pragma unroll
            for (int i = 0; i < 4; ++i) w[i] = (bf16_t)(o[db][g * 4 + i] * inv);
            *(bf16x4*)(cb + db * 32 + g * 8 + hi * 4) = w;
        }
}

// ---------------------------------------------------------------- launch
extern "C" void kernel_launch(void* const* d_in, const int* in_sizes, int n_in,
                              void* d_out, int out_size, void* d_ws, size_t ws_size,
                              hipStream_t stream) {
    const float* hs   = (const float*)d_in[0];
    const int*   pos  = (const int*)d_in[1];
    const float* wqkv = (const float*)d_in[2];
    const float* wd   = (const float*)d_in[3];
    float* out = (float*)d_out;
    char* ws = (char*)d_ws;

    bf16_t* Xb    = (bf16_t*)(ws + 0ull);           // later reused as Q
    bf16_t* Wqkvb = (bf16_t*)(ws + 33554432ull);
    bf16_t* Wdb   = (bf16_t*)(ws + 83886080ull);
    bf16_t* fused = (bf16_t*)(ws + 117440512ull);   // later reused as ctx
    bf16_t* Kb    = (bf16_t*)(ws + 167772160ull);
    bf16_t* Vt    = (bf16_t*)(ws + 176160768ull);
    bf16_t* Qb    = Xb;
    bf16_t* ctx   = fused;

    cvt3_f32_to_bf16<<<1792, 256, 0, stream>>>(hs, Xb, 16777216,
                                               wqkv, Wqkvb, 25165824,
                                               wd, Wdb, 16777216);

    gemm_qkv<<<256, 512, 0, stream>>>(Xb, Wqkvb, fused, 4096, 6144, 4096);

    rope_vt<<<8192, 256, 0, stream>>>(fused, pos, Qb, Kb, Vt);

    attn_fwd6<<<1024, 256, 0, stream>>>(Qb, Kb, Vt, ctx);

    gemm256<float><<<256, 512, 0, stream>>>(ctx, Wdb, out, 4096, 4096, 4096);
}

// Round 18
// 567.931 us; speedup vs baseline: 1.0336x; 1.0146x over previous
//
#include <hip/hip_runtime.h>

typedef __bf16 bf16_t;
typedef __bf16 bf16x8 __attribute__((ext_vector_type(8)));
typedef __bf16 bf16x4 __attribute__((ext_vector_type(4)));
typedef __bf16 bf16x2 __attribute__((ext_vector_type(2)));
typedef float  f32x4  __attribute__((ext_vector_type(4)));
typedef float  f32x16 __attribute__((ext_vector_type(16)));
typedef unsigned int u32x4 __attribute__((ext_vector_type(4)));

#define MFMA16(a, b, c) __builtin_amdgcn_mfma_f32_16x16x32_bf16((a), (b), (c), 0, 0, 0)
#define MFMA32(a, b, c) __builtin_amdgcn_mfma_f32_32x32x16_bf16((a), (b), (c), 0, 0, 0)

__device__ __forceinline__ void async_load16(const void* g, void* l) {
    __builtin_amdgcn_global_load_lds(
        (const __attribute__((address_space(1))) void*)g,
        (__attribute__((address_space(3))) void*)l, 16, 0, 0);
}

__device__ __forceinline__ unsigned pack2(float a, float b) {
    bf16x2 t;
    t[0] = (bf16_t)a;
    t[1] = (bf16_t)b;
    return __builtin_bit_cast(unsigned, t);
}

// ---------------------------------------------------------------- fp32 -> bf16 (3 tensors, one launch)
__global__ void cvt3_f32_to_bf16(const float* __restrict__ s0, bf16_t* __restrict__ d0, int n0,
                                 const float* __restrict__ s1, bf16_t* __restrict__ d1, int n1,
                                 const float* __restrict__ s2, bf16_t* __restrict__ d2, int n2) {
    const float* s; bf16_t* d; int n, bl, nb;
    const int bid = blockIdx.x;
    if (bid < 512)       { s = s0; d = d0; n = n0; bl = bid;        nb = 512; }
    else if (bid < 1280) { s = s1; d = d1; n = n1; bl = bid - 512;  nb = 768; }
    else                 { s = s2; d = d2; n = n2; bl = bid - 1280; nb = 512; }
    const int stride4 = nb * blockDim.x * 4;
    for (int j = (bl * blockDim.x + threadIdx.x) * 4; j < n; j += stride4) {
        float4 v = *(const float4*)(s + j);
        bf16x4 o = { (bf16_t)v.x, (bf16_t)v.y, (bf16_t)v.z, (bf16_t)v.w };
        *(bf16x4*)(d + j) = o;
    }
}

__device__ __forceinline__ void storeC(float* C, size_t idx, float v)  { C[idx] = v; }
__device__ __forceinline__ void storeC(bf16_t* C, size_t idx, float v) { C[idx] = (bf16_t)v; }

// ---------------------------------------------------------------- QKV GEMM (rect XCD mapping, r16-proven)
__global__ __launch_bounds__(512, 2) void gemm_qkv(const bf16_t* __restrict__ A,
                                                   const bf16_t* __restrict__ B,
                                                   bf16_t* __restrict__ C,
                                                   int M, int N, int K) {
    __shared__ __align__(16) bf16_t ldsA[2][256][64];
    __shared__ __align__(16) bf16_t ldsB[2][192][64];
    const int tid  = threadIdx.x;
    const int lane = tid & 63;
    const int wid  = tid >> 6;
    const int lrow = lane & 15, lhi = lane >> 4;
    const int wrow = (wid >> 1) * 64;
    const int wcol = (wid & 1) * 96;
    const int NT = K >> 6;

    const int xcd = (int)blockIdx.x & 7;
    const int idx = (int)blockIdx.x >> 3;
    const int rowt = (xcd >> 1) * 4 + (idx >> 3);
    const int colt = (xcd & 1) * 8 + (idx & 7);
    const size_t m0  = (size_t)rowt * 256;
    const size_t n0b = (size_t)colt * 384;

    const int cm = (((lrow & 1) << 5) | ((lrow & 2) << 3) | ((lrow & 4) << 1));

    const bf16_t* Am = A + m0 * K;

    auto stageA = [&](int bufi, int k0) {
#pragma unroll
        for (int c = 0; c < 4; ++c) {
            int q = tid + 512 * c;
            int row = q >> 3, slot = q & 7;
            int gc = (slot * 8) ^ (((row & 1) << 5) | ((row & 2) << 3) | ((row & 4) << 1));
            async_load16(Am + (size_t)row * K + k0 + gc, &ldsA[bufi][0][0] + q * 8);
        }
    };
    auto stageB = [&](const bf16_t* Bn, int bufi, int k0) {
#pragma unroll
        for (int c = 0; c < 3; ++c) {
            int q = tid + 512 * c;
            int row = q >> 3, slot = q & 7;
            int gc = (slot * 8) ^ (((row & 1) << 5) | ((row & 2) << 3) | ((row & 4) << 1));
            async_load16(Bn + (size_t)row * K + k0 + gc, &ldsB[bufi][0][0] + q * 8);
        }
    };

    for (int half = 0; half < 2; ++half) {
        const bf16_t* Bn = B + (n0b + half * 192) * K;

        f32x4 acc[4][6];
        const f32x4 vz = {0.f, 0.f, 0.f, 0.f};
#pragma unroll
        for (int i = 0; i < 4; ++i)
#pragma unroll
            for (int j = 0; j < 6; ++j) acc[i][j] = vz;

        stageA(0, 0);
        stageB(Bn, 0, 0);
        stageA(1, 64);
        stageB(Bn, 1, 64);
        asm volatile("s_waitcnt vmcnt(7)" ::: "memory");
        __builtin_amdgcn_s_barrier();

        for (int u = 0; u < NT; ++u) {
            const int cur = u & 1;
            __builtin_amdgcn_s_setprio(1);
#pragma unroll
            for (int kk = 0; kk < 2; ++kk) {
                const int cb = kk * 32 + lhi * 8;
                bf16x8 af[4], bfv[6];
#pragma unroll
                for (int i = 0; i < 4; ++i)
                    af[i] = *(const bf16x8*)(&ldsA[cur][wrow + i * 16 + lrow][0] + (cb ^ cm));
#pragma unroll
                for (int j = 0; j < 6; ++j)
                    bfv[j] = *(const bf16x8*)(&ldsB[cur][wcol + j * 16 + lrow][0] + (cb ^ cm));
#pragma unroll
                for (int i = 0; i < 4; ++i)
#pragma unroll
                    for (int j = 0; j < 6; ++j)
                        acc[i][j] = MFMA16(af[i], bfv[j], acc[i][j]);
            }
            __builtin_amdgcn_s_setprio(0);
            __builtin_amdgcn_s_barrier();
            if (u + 2 < NT) {
                stageA(cur, (u + 2) * 64);
                stageB(Bn, cur, (u + 2) * 64);
            }
            if (u == NT - 2)     asm volatile("s_waitcnt vmcnt(0)" ::: "memory");
            else if (u < NT - 2) asm volatile("s_waitcnt vmcnt(7)" ::: "memory");
            __builtin_amdgcn_s_barrier();
        }

#pragma unroll
        for (int i = 0; i < 4; ++i)
#pragma unroll
            for (int j = 0; j < 6; ++j)
#pragma unroll
                for (int r = 0; r < 4; ++r) {
                    size_t row = m0 + wrow + i * 16 + lhi * 4 + r;
                    size_t col = n0b + half * 192 + wcol + j * 16 + lrow;
                    C[row * (size_t)N + col] = (bf16_t)acc[i][j][r];
                }
    }
}

// ---------------------------------------------------------------- 256x256 GEMM (B^T), BK=64 (dense; proven)
template <typename OT>
__global__ __launch_bounds__(512, 2) void gemm256(const bf16_t* __restrict__ A,
                                                  const bf16_t* __restrict__ B,
                                                  OT* __restrict__ C,
                                                  int M, int N, int K) {
    __shared__ __align__(16) bf16_t lds[2][2][2][128][64];
    const int tid  = threadIdx.x;
    const int lane = tid & 63;
    const int wid  = tid >> 6;
    const int lrow = lane & 15, lhi = lane >> 4;
    const int wrow = (wid >> 2) * 64;
    const int wcol = (wid & 3) * 32;
    const int NT = K >> 6;
    const int nbx = N >> 8;

    const int nwg = gridDim.x;
    const int w = ((int)blockIdx.x & 7) * (nwg >> 3) + ((int)blockIdx.x >> 3);
    const size_t m0 = (size_t)(w / nbx) * 256;
    const size_t n0 = (size_t)(w % nbx) * 256;

    const int cmask = ((lrow & 1) << 5) | ((lrow & 2) << 3) | ((lrow & 4) << 1);
    const int cK0 = (lhi * 8) ^ cmask;
    const int cK1 = (32 + lhi * 8) ^ cmask;
    const int r8 = lane >> 3;
    const int gcol = ((lane & 7) * 8) ^ (((r8 & 1) << 5) | ((r8 & 2) << 3) | ((r8 & 4) << 1));

    auto stage = [&](const bf16_t* srcBase, bf16_t* region) {
#pragma unroll
        for (int c = 0; c < 2; ++c)
            async_load16(srcBase + (size_t)(c * 64 + wid * 8 + r8) * K + gcol,
                         region + c * 4096 + wid * 512);
    };

    int buf = 0;
    bf16x8 af[2][4];
    bf16x8 b0f[2][2], b1f[2][2];

    auto loadA = [&](int mh) {
#pragma unroll
        for (int i = 0; i < 4; ++i) {
            const bf16_t* rp = &lds[buf][0][mh][wrow + i * 16 + lrow][0];
            af[0][i] = *(const bf16x8*)(rp + cK0);
            af[1][i] = *(const bf16x8*)(rp + cK1);
        }
    };
    auto loadB = [&](int nh, bf16x8 (&bf)[2][2]) {
#pragma unroll
        for (int j = 0; j < 2; ++j) {
            const bf16_t* rp = &lds[buf][1][nh][wcol + j * 16 + lrow][0];
            bf[0][j] = *(const bf16x8*)(rp + cK0);
            bf[1][j] = *(const bf16x8*)(rp + cK1);
        }
    };
    auto mmacc = [&](f32x4 (&acc)[4][2], bf16x8 (&bf)[2][2]) {
#pragma unroll
        for (int kk = 0; kk < 2; ++kk)
#pragma unroll
            for (int i = 0; i < 4; ++i)
#pragma unroll
                for (int j = 0; j < 2; ++j)
                    acc[i][j] = MFMA16(af[kk][i], bf[kk][j], acc[i][j]);
    };

    f32x4 a00[4][2], a01[4][2], a10[4][2], a11[4][2];
    const f32x4 vz = {0.f, 0.f, 0.f, 0.f};
#pragma unroll
    for (int i = 0; i < 4; ++i)
#pragma unroll
        for (int j = 0; j < 2; ++j) { a00[i][j] = vz; a01[i][j] = vz; a10[i][j] = vz; a11[i][j] = vz; }

    const bf16_t* Am = A + m0 * K;
    const bf16_t* Bn = B + n0 * K;

    stage(Am,                     &lds[0][0][0][0][0]);
    stage(Bn,                     &lds[0][1][0][0][0]);
    stage(Bn + (size_t)128 * K,   &lds[0][1][1][0][0]);
    stage(Am + (size_t)128 * K,   &lds[0][0][1][0][0]);
    stage(Am + 64,                &lds[1][0][0][0][0]);
    stage(Bn + 64,                &lds[1][1][0][0][0]);
    asm volatile("s_waitcnt vmcnt(4)" ::: "memory");
    __builtin_amdgcn_s_barrier();

    for (int u = 0; u < NT; ++u, buf ^= 1) {
        loadA(0);
        loadB(0, b0f);
        loadB(1, b1f);
        __builtin_amdgcn_s_barrier();
        asm volatile("s_waitcnt lgkmcnt(0)" ::: "memory");
        if (u + 1 < NT) {
            stage(Bn + (size_t)(u + 1) * 64 + (size_t)128 * K, &lds[buf ^ 1][1][1][0][0]);
            stage(Am + (size_t)(u + 1) * 64 + (size_t)128 * K, &lds[buf ^ 1][0][1][0][0]);
        }
        __builtin_amdgcn_s_setprio(1);
        mmacc(a00, b0f);
        mmacc(a01, b1f);
        __builtin_amdgcn_s_setprio(0);
        __builtin_amdgcn_s_barrier();
        loadA(1);
        __builtin_amdgcn_s_barrier();
        asm volatile("s_waitcnt lgkmcnt(0)" ::: "memory");
        if (u + 2 < NT) {
            stage(Am + (size_t)(u + 2) * 64, &lds[buf][0][0][0][0]);
            stage(Bn + (size_t)(u + 2) * 64, &lds[buf][1][0][0][0]);
        }
        __builtin_amdgcn_s_setprio(1);
        mmacc(a10, b0f);
        mmacc(a11, b1f);
        __builtin_amdgcn_s_setprio(0);
        if (u == NT - 2)     asm volatile("s_waitcnt vmcnt(0)" ::: "memory");
        else if (u < NT - 2) asm volatile("s_waitcnt vmcnt(4)" ::: "memory");
        __builtin_amdgcn_s_barrier();
    }

    auto storeQ = [&](f32x4 (&acc)[4][2], int mq, int nq) {
#pragma unroll
        for (int i = 0; i < 4; ++i)
#pragma unroll
            for (int j = 0; j < 2; ++j)
#pragma unroll
                for (int r = 0; r < 4; ++r) {
                    size_t row = m0 + mq * 128 + wrow + i * 16 + lhi * 4 + r;
                    size_t col = n0 + nq * 128 + wcol + j * 16 + lrow;
                    storeC(C, row * (size_t)N + col, acc[i][j][r]);
                }
    };
    storeQ(a00, 0, 0); storeQ(a01, 0, 1); storeQ(a10, 1, 0); storeQ(a11, 1, 1);
}

// ---------------------------------------------------------------- fused RoPE-scatter + V-transpose
__global__ void rope_vt(const bf16_t* __restrict__ fused, const int* __restrict__ pos_ids,
                        bf16_t* __restrict__ Q, bf16_t* __restrict__ Kb,
                        bf16_t* __restrict__ Vt) {
    __shared__ bf16_t tile[32][33];
    const int bid = blockIdx.x;
    if (bid < 4096) {
        const int token = bid;
        const int b = token >> 11, s = token & 2047;
        const int d = threadIdx.x & 63;
        const int y = threadIdx.x >> 6;
        const float pos = (float)pos_ids[token];
        const float inv = __expf(-(float)d * (9.210340371976184f / 64.0f));
        float sn, c;
        sincosf(pos * inv, &sn, &c);
        const bf16_t* frow = fused + (size_t)token * 6144;
        for (int it = 0; it < 10; ++it) {
            int ss = it * 4 + y;
            int col;
            bf16_t* outp;
            if (ss < 32) {
                int h = ss, kv = h >> 2, gi = h & 3;
                col  = kv * 768 + gi * 128 + d;
                outp = Q + (((size_t)b * 32 + h) * 2048 + s) * 128 + d;
            } else {
                int kv = ss - 32;
                col  = kv * 768 + 512 + d;
                outp = Kb + (((size_t)b * 8 + kv) * 2048 + s) * 128 + d;
            }
            float x0 = (float)frow[col];
            float x1 = (float)frow[col + 64];
            outp[0]  = (bf16_t)(x0 * c - x1 * sn);
            outp[64] = (bf16_t)(x1 * c + x0 * sn);
        }
    } else {
        const int idx = bid - 4096;
        const int s0 = (idx & 63) * 32;
        const int d0 = ((idx >> 6) & 3) * 32;
        const int bk = idx >> 8;
        const int b = bk >> 3, kv = bk & 7;
        const int col0 = kv * 768 + 640 + d0;
        const int tx = threadIdx.x & 31, ty = threadIdx.x >> 5;
#pragma unroll
        for (int i = 0; i < 4; i++) {
            int sy = ty + i * 8;
            tile[sy][tx] = fused[((size_t)b * 2048 + s0 + sy) * 6144 + col0 + tx];
        }
        __syncthreads();
#pragma unroll
        for (int i = 0; i < 4; i++) {
            int dy = ty + i * 8;
            Vt[((size_t)bk * 128 + d0 + dy) * 2048 + s0 + tx] = tile[tx][dy];
        }
    }
}

// ---------------------------------------------------------------- flash attention v6 (proven)
__global__ __launch_bounds__(256) void attn_fwd6(const bf16_t* __restrict__ Q,
                                                 const bf16_t* __restrict__ Kb,
                                                 const bf16_t* __restrict__ Vt,
                                                 bf16_t* __restrict__ ctx) {
    __shared__ __align__(16) bf16_t Ks[2][32][128];
    __shared__ __align__(16) bf16_t Vs[2][128][32];
    const int tid  = threadIdx.x;
    const int lane = tid & 63;
    const int wid  = tid >> 6;
    const int l31  = lane & 31;
    const int hi   = lane >> 5;

    const int bidx  = blockIdx.x;
    const int slot  = bidx >> 8;
    const int rr    = (bidx >> 4) & 15;
    const int combo = bidx & 15;
    const int b     = combo & 1;
    const int kvh   = combo >> 1;
    int qt;
    switch (slot) {
        case 0: qt = rr;      break;
        case 1: qt = 63 - rr; break;
        case 2: qt = 16 + rr; break;
        default: qt = 47 - rr; break;
    }
    const int q0 = qt * 32;
    const int h  = kvh * 4 + wid;

    const bf16_t* kbase = Kb + (((size_t)b * 8 + kvh) * 2048) * 128;
    const bf16_t* vbase = Vt + (((size_t)b * 8 + kvh) * 128) * 2048;
    const float kl = 0.12750062133361622f;

    auto stageKV = [&](int bufi, int kv0) {
#pragma unroll
        for (int c = 0; c < 2; ++c) {
            int q = tid + 256 * c;
            int r = q >> 4;
            int cl = ((q & 15) * 16) ^ ((r & 7) << 4);
            async_load16(kbase + (size_t)(kv0 + r) * 128 + (cl >> 1),
                         &Ks[bufi][0][0] + q * 8);
        }
#pragma unroll
        for (int c = 0; c < 2; ++c) {
            int q = tid + 256 * c;
            int d = q >> 2;
            int cl = ((q & 3) * 16) ^ ((d & 3) << 4);
            async_load16(vbase + (size_t)d * 2048 + kv0 + (cl >> 1),
                         &Vs[bufi][0][0] + q * 8);
        }
    };

    const bf16_t* qbase = Q + (((size_t)b * 32 + h) * 2048 + q0) * 128;
    bf16x8 qf[8];
#pragma unroll
    for (int kc = 0; kc < 8; ++kc)
        qf[kc] = *(const bf16x8*)(qbase + (size_t)l31 * 128 + kc * 16 + hi * 8);

    f32x16 o[4];
#pragma unroll
    for (int db = 0; db < 4; ++db)
#pragma unroll
        for (int r = 0; r < 16; ++r) o[db][r] = 0.f;
    float m = -1e30f, lsum = 0.f;

    const int kxor = (l31 & 7) << 3;
    const int vxor = (l31 & 3) << 3;

    stageKV(0, 0);
    __syncthreads();

    int buf = 0;
    for (int st = 0; st <= qt; ++st, buf ^= 1) {
        if (st < qt) stageKV(buf ^ 1, (st + 1) * 32);

        const bf16_t* krow = &Ks[buf][l31][0];
        f32x16 s;
#pragma unroll
        for (int r = 0; r < 16; ++r) s[r] = 0.f;
#pragma unroll
        for (int kc = 0; kc < 8; kc += 2) {
            bf16x8 k0 = *(const bf16x8*)(krow + ((kc * 16 + hi * 8) ^ kxor));
            bf16x8 k1 = *(const bf16x8*)(krow + (((kc + 1) * 16 + hi * 8) ^ kxor));
            s = MFMA32(k0, qf[kc], s);
            s = MFMA32(k1, qf[kc + 1], s);
        }

        if (st == qt) {
            const int qg = q0 + l31;
            const int kv0 = st * 32;
#pragma unroll
            for (int r = 0; r < 16; ++r) {
                int kvg = kv0 + (r & 3) + 8 * (r >> 2) + 4 * hi;
                if (kvg > qg) s[r] = -1e30f;
            }
        }
        float mx01 = fmaxf(s[0], s[1]);
#pragma unroll
        for (int r = 2; r < 16; r += 2) mx01 = fmaxf(mx01, fmaxf(s[r], s[r + 1]));
        float pmax = fmaxf(mx01, __shfl_xor(mx01, 32, 64));
        if (pmax > m + 90.5f) {
            float corr = exp2f((m - pmax) * kl);
            lsum *= corr;
#pragma unroll
            for (int db = 0; db < 4; ++db)
#pragma unroll
                for (int r = 0; r < 16; ++r) o[db][r] *= corr;
            m = pmax;
        }
        const float mk = m * kl;
        float ps4[4] = {0.f, 0.f, 0.f, 0.f};
#pragma unroll
        for (int r = 0; r < 16; ++r) {
            float e = exp2f(fmaf(s[r], kl, -mk));
            s[r] = e;
            ps4[r & 3] += e;
        }
        lsum += (ps4[0] + ps4[1]) + (ps4[2] + ps4[3]);

#pragma unroll
        for (int ks = 0; ks < 2; ++ks) {
            unsigned u0 = pack2(s[ks * 8 + 0], s[ks * 8 + 1]);
            unsigned u1 = pack2(s[ks * 8 + 2], s[ks * 8 + 3]);
            unsigned u2 = pack2(s[ks * 8 + 4], s[ks * 8 + 5]);
            unsigned u3 = pack2(s[ks * 8 + 6], s[ks * 8 + 7]);
            unsigned t0 = __shfl_xor(u0, 32, 64);
            unsigned t1 = __shfl_xor(u1, 32, 64);
            unsigned t2 = __shfl_xor(u2, 32, 64);
            unsigned t3 = __shfl_xor(u3, 32, 64);
            u32x4 uw;
            uw[0] = hi ? t2 : u0;
            uw[1] = hi ? t3 : u1;
            uw[2] = hi ? u2 : t0;
            uw[3] = hi ? u3 : t1;
            bf16x8 pb = __builtin_bit_cast(bf16x8, uw);
            const int vcol = (ks * 16 + hi * 8) ^ vxor;
#pragma unroll
            for (int db = 0; db < 4; ++db) {
                bf16x8 vf = *(const bf16x8*)(&Vs[buf][db * 32 + l31][0] + vcol);
                o[db] = MFMA32(vf, pb, o[db]);
            }
        }
        __syncthreads();
    }

    float lall = lsum + __shfl_xor(lsum, 32, 64);
    const float inv = 1.0f / lall;
    bf16_t* cb = ctx + ((size_t)(b * 2048 + q0 + l31)) * 4096 + h * 128;
#pragma unroll
    for (int db = 0; db < 4; ++db)
#pragma unroll
        for (int g = 0; g < 4; ++g) {
            bf16x4 w;
#pragma unroll
            for (int i = 0; i < 4; ++i) w[i] = (bf16_t)(o[db][g * 4 + i] * inv);
            *(bf16x4*)(cb + db * 32 + g * 8 + hi * 4) = w;
        }
}

// ---------------------------------------------------------------- launch
extern "C" void kernel_launch(void* const* d_in, const int* in_sizes, int n_in,
                              void* d_out, int out_size, void* d_ws, size_t ws_size,
                              hipStream_t stream) {
    const float* hs   = (const float*)d_in[0];
    const int*   pos  = (const int*)d_in[1];
    const float* wqkv = (const float*)d_in[2];
    const float* wd   = (const float*)d_in[3];
    float* out = (float*)d_out;
    char* ws = (char*)d_ws;

    bf16_t* Xb    = (bf16_t*)(ws + 0ull);           // later reused as Q
    bf16_t* Wqkvb = (bf16_t*)(ws + 33554432ull);
    bf16_t* Wdb   = (bf16_t*)(ws + 83886080ull);
    bf16_t* fused = (bf16_t*)(ws + 117440512ull);   // later reused as ctx
    bf16_t* Kb    = (bf16_t*)(ws + 167772160ull);
    bf16_t* Vt    = (bf16_t*)(ws + 176160768ull);
    bf16_t* Qb    = Xb;
    bf16_t* ctx   = fused;

    cvt3_f32_to_bf16<<<1792, 256, 0, stream>>>(hs, Xb, 16777216,
                                               wqkv, Wqkvb, 25165824,
                                               wd, Wdb, 16777216);

    gemm_qkv<<<256, 512, 0, stream>>>(Xb, Wqkvb, fused, 4096, 6144, 4096);

    rope_vt<<<8192, 256, 0, stream>>>(fused, pos, Qb, Kb, Vt);

    attn_fwd6<<<1024, 256, 0, stream>>>(Qb, Kb, Vt, ctx);

    gemm256<float><<<256, 512, 0, stream>>>(ctx, Wdb, out, 4096, 4096, 4096);
}